// Round 18
// baseline (248.309 us; speedup 1.0000x reference)
//
#include <hip/hip_runtime.h>
#include <hip/hip_bf16.h>

#define L_SEQ  2048
#define NBATCH 2
#define DMODEL 1024
#define DINNER 2048
#define DSTATE 16
#define DTRANK 64
#define MROWS  (L_SEQ * NBATCH)   // 4096
#define NCHUNK 64
#define LCHUNK 32                 // L_SEQ / NCHUNK
#define LOG2E  1.44269504f

using bf16 = __hip_bfloat16;
typedef short s16x8 __attribute__((ext_vector_type(8)));   // 8 bf16 = 16B
typedef float f32x4 __attribute__((ext_vector_type(4)));

__device__ __forceinline__ void gload_lds16(const bf16* g, bf16* l) {
    __builtin_amdgcn_global_load_lds(
        (const __attribute__((address_space(1))) void*)g,
        (__attribute__((address_space(3))) void*)l, 16, 0, 0);
}

__device__ __forceinline__ float bf2f(short v) {
    return __uint_as_float(((unsigned)(unsigned short)v) << 16);
}

// ---------------------------------------------------------------------------
// 256x256 MFMA GEMM, 2-barrier deep pipeline.
// ---------------------------------------------------------------------------
__global__ __launch_bounds__(512, 2)
void gemm256(const bf16* __restrict__ A, const bf16* __restrict__ Bt,
             bf16* __restrict__ C, int N, int K, int lda, int ldb)
{
    __shared__ __align__(16) bf16 As[2][256 * 64];
    __shared__ __align__(16) bf16 Bs[2][256 * 64];

    const int tid  = threadIdx.x;
    const int wid  = tid >> 6;
    const int lane = tid & 63;
    const int wr = wid >> 2, wc = wid & 3;       // 2x4 wave grid
    const int fr = lane & 15, fk = lane >> 4;

    const int orig = blockIdx.y * gridDim.x + blockIdx.x;
    const int xcd  = orig & 7, k = orig >> 3;
    const int byi  = (xcd >> 1) * 4 + (k >> 3);
    const int bxi  = (xcd & 1) * 8 + (k & 7);
    const long bm = (long)byi * 256;
    const long bn = (long)bxi * 256;

    const int q0 = tid, q1 = tid + 512;
    const int r0 = q0 >> 3, r1 = q1 >> 3;
    const int c0 = ((q0 & 7) ^ (r0 & 7)) << 3;
    const int c1 = ((q1 & 7) ^ (r1 & 7)) << 3;
    const bf16* sA0h0 = A  + (bm + r0)       * (long)lda + c0;
    const bf16* sA1h0 = A  + (bm + r1)       * (long)lda + c1;
    const bf16* sA0h1 = A  + (bm + 128 + r0) * (long)lda + c0;
    const bf16* sA1h1 = A  + (bm + 128 + r1) * (long)lda + c1;
    const bf16* sB0h0 = Bt + (bn + r0)       * (long)ldb + c0;
    const bf16* sB1h0 = Bt + (bn + r1)       * (long)ldb + c1;
    const bf16* sB0h1 = Bt + (bn + 128 + r0) * (long)ldb + c0;
    const bf16* sB1h1 = Bt + (bn + 128 + r1) * (long)ldb + c1;
    const int dst0 = wid * 512;
    const int dst1 = 4096 + wid * 512;

    const int o0   = ((fk ^ (fr & 7)) << 3);
    const int o1   = o0 ^ 32;
    const int rA64 = (wr * 64 + fr) * 64;
    const int rB64 = (wc * 32 + fr) * 64;

    f32x4 acc[8][4] = {};
    s16x8 af[4][2], bf0[2][2], bf1[2][2];
    const int nt = K >> 6;

#define STAGE(ARR, BUF, H, P0, P1) do {                    \
        gload_lds16(P0, &ARR[BUF][(H) * 8192 + dst0]);     \
        gload_lds16(P1, &ARR[BUF][(H) * 8192 + dst1]);     \
        P0 += 64; P1 += 64;                                \
    } while (0)

#define LOADA(MH, CUR) do {                                   \
        const bf16* ab = &As[CUR][rA64 + (MH) * 8192];        \
        _Pragma("unroll") for (int m = 0; m < 4; ++m) {       \
            af[m][0] = *(const s16x8*)&ab[m * 1024 + o0];     \
            af[m][1] = *(const s16x8*)&ab[m * 1024 + o1]; }   \
    } while (0)

#define LOADB(NH, CUR, BF) do {                               \
        const bf16* bb = &Bs[CUR][rB64 + (NH) * 8192];        \
        _Pragma("unroll") for (int n = 0; n < 2; ++n) {       \
            BF[n][0] = *(const s16x8*)&bb[n * 1024 + o0];     \
            BF[n][1] = *(const s16x8*)&bb[n * 1024 + o1]; }   \
    } while (0)

#define MFMAQ(MH, NH, BF) do {                                               \
        __builtin_amdgcn_s_setprio(1);                                       \
        _Pragma("unroll") for (int ks = 0; ks < 2; ++ks)                     \
        _Pragma("unroll") for (int m = 0; m < 4; ++m)                        \
        _Pragma("unroll") for (int n = 0; n < 2; ++n)                        \
            acc[(MH) * 4 + m][(NH) * 2 + n] =                                \
                __builtin_amdgcn_mfma_f32_16x16x32_bf16(                     \
                    af[m][ks], BF[n][ks], acc[(MH) * 4 + m][(NH) * 2 + n],   \
                    0, 0, 0);                                                \
        __builtin_amdgcn_s_setprio(0);                                       \
    } while (0)

#define WB(NV) asm volatile("s_waitcnt vmcnt(" #NV ")\n\ts_barrier" ::: "memory")

    STAGE(As, 0, 0, sA0h0, sA1h0);
    STAGE(Bs, 0, 0, sB0h0, sB1h0);
    STAGE(Bs, 0, 1, sB0h1, sB1h1);
    STAGE(As, 0, 1, sA0h1, sA1h1);

    int cur = 0;
    for (int t = 0; t < nt; ++t) {
        WB(2);                               // A0,B0,B1 of t ready; A1 in flight
        LOADA(0, cur);
        LOADB(0, cur, bf0);
        LOADB(1, cur, bf1);
        if (t + 1 < nt) {
            STAGE(As, cur ^ 1, 0, sA0h0, sA1h0);
            STAGE(Bs, cur ^ 1, 0, sB0h0, sB1h0);
            STAGE(Bs, cur ^ 1, 1, sB0h1, sB1h1);
            STAGE(As, cur ^ 1, 1, sA0h1, sA1h1);
        }
        MFMAQ(0, 0, bf0);
        MFMAQ(0, 1, bf1);
        if (t + 1 < nt) WB(8); else WB(0);   // A1 of t ready
        LOADA(1, cur);
        MFMAQ(1, 1, bf1);
        MFMAQ(1, 0, bf0);
        cur ^= 1;
    }

#undef STAGE
#undef LOADA
#undef LOADB
#undef MFMAQ
#undef WB

    #pragma unroll
    for (int mh = 0; mh < 2; ++mh)
    #pragma unroll
    for (int m = 0; m < 4; ++m)
    #pragma unroll
    for (int nh = 0; nh < 2; ++nh)
    #pragma unroll
    for (int n = 0; n < 2; ++n) {
        f32x4 v = acc[mh * 4 + m][nh * 2 + n];
        long row0 = bm + wr * 64 + mh * 128 + m * 16 + fk * 4;
        long col  = bn + wc * 32 + nh * 128 + n * 16 + fr;
        #pragma unroll
        for (int j = 0; j < 4; ++j)
            C[(row0 + j) * N + col] = __float2bfloat16(v[j]);
    }
}

// ---------------------------------------------------------------------------
// MFMA bf16 GEMM: 128x128 tile, BK=32, 512 threads = 8 waves (4Mx2N; per-wave
// 32x64), COUNTED 2-deep pipeline.
// ---------------------------------------------------------------------------
template<typename OutT, int EPI, bool SPLITK = false>
__global__ __launch_bounds__(512)
void gemm_bt(const bf16* __restrict__ A, const bf16* __restrict__ Bt,
             OutT* __restrict__ C, const float* __restrict__ bias,
             int M, int N, int K, int lda, int ldb)
{
    __shared__ __align__(16) bf16 As[2][128 * 32];
    __shared__ __align__(16) bf16 Bs[2][128 * 32];

    const int tid  = threadIdx.x;          // 0..511
    const int wid  = tid >> 6;             // 0..7
    const int lane = tid & 63;
    const int wr = wid >> 1, wc = wid & 1; // 4x2 wave grid, per-wave 32x64
    const int fr = lane & 15, fk = lane >> 4;

    const int nbx = gridDim.x;
    const int nwg = nbx * gridDim.y;
    int id  = blockIdx.y * nbx + blockIdx.x;
    if (nwg >= 8) {
        int cpx = nwg >> 3;
        id = (id & 7) * cpx + (id >> 3);
    }
    const int bxi = id % nbx, byi = id / nbx;
    const long bm = (long)byi * 128;
    const long bn = (long)bxi * 128;

    if constexpr (SPLITK) {
        long ko = (long)blockIdx.z * K;
        A  += ko;
        Bt += ko;
        C  += (size_t)blockIdx.z * M * N;
    }

    const int r0 = tid >> 2, c0 = (tid & 3) << 3;
    const bf16* pA = A  + (bm + r0) * (long)lda + c0;
    const bf16* pB = Bt + (bn + r0) * (long)ldb + c0;
    const size_t ld = (size_t)wid * 512;

    f32x4 acc[2][4] = {};
    const int nt = K >> 5;

#define STG(BUF) do {                             \
        gload_lds16(pA, &As[BUF][ld]);            \
        gload_lds16(pB, &Bs[BUF][ld]);            \
        pA += 32; pB += 32;                       \
    } while (0)

    STG(0);                       // tile 0: 2 in flight
    if (nt > 1) STG(1);           // tile 1: 4 in flight

    int cur = 0;
    for (int t = 0; t < nt; ++t) {
        if (t + 1 < nt)
            asm volatile("s_waitcnt vmcnt(2)\n\ts_barrier" ::: "memory");
        else
            asm volatile("s_waitcnt vmcnt(0)\n\ts_barrier" ::: "memory");

        s16x8 afrag[2], bfrag[4];
        #pragma unroll
        for (int m = 0; m < 2; ++m)
            afrag[m] = *(const s16x8*)&As[cur][(wr * 32 + m * 16 + fr) * 32 + fk * 8];
        #pragma unroll
        for (int n = 0; n < 4; ++n)
            bfrag[n] = *(const s16x8*)&Bs[cur][(wc * 64 + n * 16 + fr) * 32 + fk * 8];

        #pragma unroll
        for (int m = 0; m < 2; ++m)
            #pragma unroll
            for (int n = 0; n < 4; ++n)
                acc[m][n] = __builtin_amdgcn_mfma_f32_16x16x32_bf16(
                    afrag[m], bfrag[n], acc[m][n], 0, 0, 0);

        if (t + 2 < nt) {
            asm volatile("s_waitcnt lgkmcnt(0)\n\ts_barrier" ::: "memory");
            STG(cur);             // stage tile t+2 into the freed buffer
        }
        cur ^= 1;
    }
#undef STG

    #pragma unroll
    for (int m = 0; m < 2; ++m)
        #pragma unroll
        for (int n = 0; n < 4; ++n) {
            f32x4 v = acc[m][n];
            long row0 = bm + wr * 32 + m * 16 + fk * 4;
            long col  = bn + wc * 64 + n * 16 + fr;
            #pragma unroll
            for (int j = 0; j < 4; ++j) {
                float val = v[j];
                if (EPI == 1) {
                    val += bias[col];
                    val = (val > 20.f) ? val : log1pf(__expf(val));
                }
                if constexpr (sizeof(OutT) == 2)
                    C[(row0 + j) * N + col] = __float2bfloat16(val);
                else
                    C[(row0 + j) * N + col] = val;
            }
        }
}

// ---------------------------------------------------------------------------
// Fused preprocessing: 4 weight transposes + convert_x in ONE kernel
// ---------------------------------------------------------------------------
__device__ __forceinline__ void do_transpose(
    const float* __restrict__ in, bf16* __restrict__ out,
    int R, int C, int Cpad, int bx, int by, int tx, int ty)
{
    __shared__ float tile[32][33];
    int cb = bx * 32, rb = by * 32;
    #pragma unroll
    for (int i = 0; i < 4; ++i) {
        int r = rb + ty + i * 8, c = cb + tx;
        tile[ty + i * 8][tx] = (r < R && c < C) ? in[(long)r * C + c] : 0.f;
    }
    __syncthreads();
    #pragma unroll
    for (int i = 0; i < 4; ++i) {
        int oc = cb + ty + i * 8;
        int orow = rb + tx;
        if (oc < Cpad && orow < R)
            out[(long)oc * R + orow] = __float2bfloat16(tile[tx][ty + i * 8]);
    }
}

__global__ __launch_bounds__(256)
void prep_kernel(const float* __restrict__ W_in,  bf16* __restrict__ WinT,
                 const float* __restrict__ W_x,   bf16* __restrict__ WxT,
                 const float* __restrict__ W_dt,  bf16* __restrict__ WdtT,
                 const float* __restrict__ W_out, bf16* __restrict__ WoutT,
                 const float* __restrict__ x,     bf16* __restrict__ Xb)
{
    const int b  = blockIdx.x;
    const int t  = threadIdx.x;
    const int tx = t & 31, ty = t >> 5;

    if (b < 4096) {                       // W_in (1024,4096) -> (4096,1024)
        do_transpose(W_in, WinT, 1024, 4096, 4096, b & 127, b >> 7, tx, ty);
    } else if (b < 4352) {                // W_x (2048,96) -> (128,2048)
        int b2 = b - 4096;
        do_transpose(W_x, WxT, 2048, 96, 128, b2 & 3, b2 >> 2, tx, ty);
    } else if (b < 4480) {                // W_dt (64,2048) -> (2048,64)
        int b3 = b - 4352;
        do_transpose(W_dt, WdtT, 64, 2048, 2048, b3 & 63, b3 >> 6, tx, ty);
    } else if (b < 6528) {                // W_out (2048,1024) -> (1024,2048)
        int b4 = b - 4480;
        do_transpose(W_out, WoutT, 2048, 1024, 1024, b4 & 31, b4 >> 5, tx, ty);
    } else {                              // x (L,B,DM) -> Xb (B*L,DM) bf16
        int idx = (b - 6528) * 256 + t;
        int c   = idx & (DMODEL - 1);
        int row = idx >> 10;
        int l   = row & (L_SEQ - 1);
        int bb  = row >> 11;
        Xb[idx] = __float2bfloat16(x[((l * NBATCH + bb) << 10) | c]);
    }
}

// depthwise causal conv (d_conv=4) + silu, 8 channels per thread (vectorized)
__global__ void conv_silu_kernel(const bf16* __restrict__ xr, const float* __restrict__ Wc,
                                 const float* __restrict__ bc, bf16* __restrict__ u)
{
    int idx = blockIdx.x * 256 + threadIdx.x;   // MROWS*DINNER/8 threads
    int g   = idx & 255;
    int row = idx >> 8;
    int c   = g << 3;
    int l   = row & (L_SEQ - 1);

    float acc[8];
    f32x4 bi0 = *(const f32x4*)(bc + c);
    f32x4 bi1 = *(const f32x4*)(bc + c + 4);
    #pragma unroll
    for (int j = 0; j < 4; ++j) { acc[j] = bi0[j]; acc[4 + j] = bi1[j]; }

    f32x4 w[8];
    #pragma unroll
    for (int j = 0; j < 8; ++j) w[j] = *(const f32x4*)(Wc + (c + j) * 4);

    #pragma unroll
    for (int t = 0; t < 4; ++t) {
        int ll = l - 3 + t;
        if (ll >= 0) {
            s16x8 v = *(const s16x8*)(xr + (long)(row - 3 + t) * 4096 + c);
            #pragma unroll
            for (int j = 0; j < 8; ++j)
                acc[j] += bf2f(v[j]) * w[j][t];
        }
    }
    s16x8 o;
    #pragma unroll
    for (int j = 0; j < 8; ++j) {
        float a = acc[j];
        float s = a / (1.f + __builtin_amdgcn_exp2f(-LOG2E * a));
        bf16 h = __float2bfloat16(s);
        o[j] = *(short*)&h;
    }
    *(s16x8*)(u + (long)row * DINNER + c) = o;
}

// sum 8 split-K partials -> xdbl fp32; also emit drbf (cols 0..63 as bf16)
__global__ void reduce_xdbl(const float* __restrict__ part, float* __restrict__ xdbl,
                            bf16* __restrict__ drbf)
{
    int idx = blockIdx.x * 256 + threadIdx.x;
    const size_t stride = (size_t)MROWS * 128;
    float v = 0.f;
    #pragma unroll
    for (int z = 0; z < 8; ++z)
        v += part[idx + z * stride];
    xdbl[idx] = v;
    int col = idx & 127;
    if (col < 64)
        drbf[(idx >> 7) * 64 + col] = __float2bfloat16(v);
}

// ---------------------------------------------------------------------------
// Chunked parallel selective scan — round-9 form (frozen). delta bf16.
// FAST PATH (runtime-checked): A[d][n] = -(n+1) => powers of exp(-dl).
// ---------------------------------------------------------------------------
__global__ __launch_bounds__(256)
void scan_phase1(const bf16* __restrict__ delta, const bf16* __restrict__ u,
                 const float* __restrict__ xdbl, const float* __restrict__ A_log,
                 float* __restrict__ AS)
{
    const int idx   = blockIdx.x * 256 + threadIdx.x;
    const int half  = idx & 1;
    const int ch    = idx >> 1;
    const int chunk = blockIdx.y;
    const int d     = ch & (DINNER - 1);
    const int b     = ch >> 11;
    const int n0    = half * 8;

    float A2[8], s[8];
    const f32x4* Arow = (const f32x4*)(A_log + d * DSTATE + n0);
    #pragma unroll
    for (int q = 0; q < 2; ++q) {
        f32x4 v = Arow[q];
        #pragma unroll
        for (int j = 0; j < 4; ++j) A2[q * 4 + j] = -__expf(v[j]) * LOG2E;
    }
    #pragma unroll
    for (int n = 0; n < 8; ++n) s[n] = 0.f;
    float sdl = 0.f;

    bool fastA = true;
    #pragma unroll
    for (int j = 0; j < 8; ++j)
        fastA &= fabsf(A2[j] + (float)(n0 + j + 1) * LOG2E)
                 < 0.01f * (float)(n0 + j + 1);

    const long row0 = (long)b * L_SEQ + chunk * LCHUNK;
    const bf16*  pD = delta + row0 * DINNER + d;
    const bf16*  pU = u     + row0 * DINNER + d;
    const f32x4* pB = (const f32x4*)(xdbl + row0 * 128 + 64 + n0);

    if (fastA) {
        #pragma unroll 4
        for (int l = 0; l < LCHUNK; ++l) {
            float dl = __bfloat162float(*pD);
            float uv = __bfloat162float(*pU);
            f32x4 B0 = pB[0], B1 = pB[1];
            pD += DINNER; pU += DINNER; pB += 32;
            float dbu = dl * uv;
            sdl += dl;
            float b1 = __builtin_amdgcn_exp2f(-LOG2E * dl);   // exp(-dl)
            float b2 = b1 * b1, b3 = b2 * b1, b4 = b2 * b2;
            float b5 = b4 * b1, b6 = b4 * b2, b7 = b4 * b3, b8 = b4 * b4;
            float pre = half ? b8 : 1.f;
            s[0] = pre * b1 * s[0] + dbu * B0[0];
            s[1] = pre * b2 * s[1] + dbu * B0[1];
            s[2] = pre * b3 * s[2] + dbu * B0[2];
            s[3] = pre * b4 * s[3] + dbu * B0[3];
            s[4] = pre * b5 * s[4] + dbu * B1[0];
            s[5] = pre * b6 * s[5] + dbu * B1[1];
            s[6] = pre * b7 * s[6] + dbu * B1[2];
            s[7] = pre * b8 * s[7] + dbu * B1[3];
        }
    } else {
        #pragma unroll 4
        for (int l = 0; l < LCHUNK; ++l) {
            float dl = __bfloat162float(*pD);
            float uv = __bfloat162float(*pU);
            f32x4 B0 = pB[0], B1 = pB[1];
            pD += DINNER; pU += DINNER; pB += 32;
            float dbu = dl * uv;
            sdl += dl;
            #pragma unroll
            for (int j = 0; j < 4; ++j) {
                float e = __builtin_amdgcn_exp2f(dl * A2[j]);
                s[j] = e * s[j] + dbu * B0[j];
            }
            #pragma unroll
            for (int j = 0; j < 4; ++j) {
                float e = __builtin_amdgcn_exp2f(dl * A2[4 + j]);
                s[4 + j] = e * s[4 + j] + dbu * B1[j];
            }
        }
    }
    float ap[8];
    #pragma unroll
    for (int n = 0; n < 8; ++n) ap[n] = __builtin_amdgcn_exp2f(sdl * A2[n]);

    float* o = AS + ((size_t)chunk * 4096 + ch) * 32 + n0;
    *(f32x4*)(o)      = *(f32x4*)&ap[0];
    *(f32x4*)(o + 4)  = *(f32x4*)&ap[4];
    *(f32x4*)(o + 16) = *(f32x4*)&s[0];
    *(f32x4*)(o + 20) = *(f32x4*)&s[4];
}

__global__ __launch_bounds__(256)
void scan_phase2(float* __restrict__ AS)
{
    const int idx = blockIdx.x * 256 + threadIdx.x;
    const int n   = idx & 15;
    const int ch  = idx >> 4;

    float s = 0.f;
    for (int cb = 0; cb < NCHUNK; cb += 16) {
        float av[16], sv[16];
        #pragma unroll
        for (int j = 0; j < 16; ++j) {
            size_t r = ((size_t)(cb + j) * 4096 + ch) * 32 + n;
            av[j] = AS[r];
            sv[j] = AS[r + 16];
        }
        #pragma unroll
        for (int j = 0; j < 16; ++j) {
            AS[((size_t)(cb + j) * 4096 + ch) * 32 + 16 + n] = s;
            s = av[j] * s + sv[j];
        }
    }
}

__global__ __launch_bounds__(256)
void scan_phase3(const bf16* __restrict__ delta, const bf16* __restrict__ u,
                 const float* __restrict__ xdbl, const bf16* __restrict__ xr,
                 const float* __restrict__ AS, const float* __restrict__ A_log,
                 const float* __restrict__ Dp, bf16* __restrict__ ybf)
{
    const int idx   = blockIdx.x * 256 + threadIdx.x;
    const int half  = idx & 1;
    const int ch    = idx >> 1;
    const int chunk = blockIdx.y;
    const int d     = ch & (DINNER - 1);
    const int b     = ch >> 11;
    const int n0    = half * 8;

    float A2[8], s[8];
    const f32x4* Arow = (const f32x4*)(A_log + d * DSTATE + n0);
    #pragma unroll
    for (int q = 0; q < 2; ++q) {
        f32x4 v = Arow[q];
        #pragma unroll
        for (int j = 0; j < 4; ++j) A2[q * 4 + j] = -__expf(v[j]) * LOG2E;
    }
    const float* ip = AS + ((size_t)chunk * 4096 + ch) * 32 + 16 + n0;
    *(f32x4*)&s[0] = *(const f32x4*)(ip);
    *(f32x4*)&s[4] = *(const f32x4*)(ip + 4);

    bool fastA = true;
    #pragma unroll
    for (int j = 0; j < 8; ++j)
        fastA &= fabsf(A2[j] + (float)(n0 + j + 1) * LOG2E)
                 < 0.01f * (float)(n0 + j + 1);

    const float Dd  = Dp[d];
    const long row0 = (long)b * L_SEQ + chunk * LCHUNK;

    const bf16*  pD = delta + row0 * DINNER + d;
    const bf16*  pU = u     + row0 * DINNER + d;
    const bf16*  pR = xr    + row0 * 4096 + 2048 + d;
    const f32x4* pB = (const f32x4*)(xdbl + row0 * 128 + 64 + n0);
    bf16*        pY = ybf   + row0 * DINNER + d;

    if (fastA) {
        #pragma unroll 4
        for (int l = 0; l < LCHUNK; ++l) {
            float dl = __bfloat162float(*pD);
            float uv = __bfloat162float(*pU);
            float rs = __bfloat162float(*pR);
            f32x4 B0 = pB[0], B1 = pB[1];
            f32x4 C0 = pB[4], C1 = pB[5];
            pD += DINNER; pU += DINNER; pR += 4096; pB += 32;
            float dbu = dl * uv;
            float b1 = __builtin_amdgcn_exp2f(-LOG2E * dl);   // exp(-dl)
            float b2 = b1 * b1, b3 = b2 * b1, b4 = b2 * b2;
            float b5 = b4 * b1, b6 = b4 * b2, b7 = b4 * b3, b8 = b4 * b4;
            float pre = half ? b8 : 1.f;
            float y0 = 0.f, y1 = 0.f;
            s[0] = pre * b1 * s[0] + dbu * B0[0];  y0 += s[0] * C0[0];
            s[1] = pre * b2 * s[1] + dbu * B0[1];  y0 += s[1] * C0[1];
            s[2] = pre * b3 * s[2] + dbu * B0[2];  y0 += s[2] * C0[2];
            s[3] = pre * b4 * s[3] + dbu * B0[3];  y0 += s[3] * C0[3];
            s[4] = pre * b5 * s[4] + dbu * B1[0];  y1 += s[4] * C1[0];
            s[5] = pre * b6 * s[5] + dbu * B1[1];  y1 += s[5] * C1[1];
            s[6] = pre * b7 * s[6] + dbu * B1[2];  y1 += s[6] * C1[2];
            s[7] = pre * b8 * s[7] + dbu * B1[3];  y1 += s[7] * C1[3];
            float yh = y0 + y1;
            float yt = yh + __shfl_xor(yh, 1);
            if (half == 0) {
                float yf = yt + uv * Dd;
                yf *= rs / (1.f + __builtin_amdgcn_exp2f(-LOG2E * rs));
                *pY = __float2bfloat16(yf);
            }
            pY += DINNER;
        }
    } else {
        #pragma unroll 4
        for (int l = 0; l < LCHUNK; ++l) {
            float dl = __bfloat162float(*pD);
            float uv = __bfloat162float(*pU);
            float rs = __bfloat162float(*pR);
            f32x4 B0 = pB[0], B1 = pB[1];
            f32x4 C0 = pB[4], C1 = pB[5];
            pD += DINNER; pU += DINNER; pR += 4096; pB += 32;
            float dbu = dl * uv;
            float y0 = 0.f, y1 = 0.f;
            #pragma unroll
            for (int j = 0; j < 4; ++j) {
                float e = __builtin_amdgcn_exp2f(dl * A2[j]);
                s[j] = e * s[j] + dbu * B0[j];
                y0 += s[j] * C0[j];
            }
            #pragma unroll
            for (int j = 0; j < 4; ++j) {
                float e = __builtin_amdgcn_exp2f(dl * A2[4 + j]);
                s[4 + j] = e * s[4 + j] + dbu * B1[j];
                y1 += s[4 + j] * C1[j];
            }
            float yh = y0 + y1;
            float yt = yh + __shfl_xor(yh, 1);
            if (half == 0) {
                float yf = yt + uv * Dd;
                yf *= rs / (1.f + __builtin_amdgcn_exp2f(-LOG2E * rs));
                *pY = __float2bfloat16(yf);
            }
            pY += DINNER;
        }
    }
}

// ---------------------------------------------------------------------------
extern "C" void kernel_launch(void* const* d_in, const int* in_sizes, int n_in,
                              void* d_out, int out_size, void* d_ws, size_t ws_size,
                              hipStream_t stream)
{
    const float* x      = (const float*)d_in[0];
    const float* W_in   = (const float*)d_in[1];
    const float* W_conv = (const float*)d_in[2];
    const float* b_conv = (const float*)d_in[3];
    const float* W_x    = (const float*)d_in[4];
    const float* W_dt   = (const float*)d_in[5];
    const float* b_dt   = (const float*)d_in[6];
    const float* A_log  = (const float*)d_in[7];
    const float* Dp     = (const float*)d_in[8];
    const float* W_out  = (const float*)d_in[9];
    float* out = (float*)d_out;

    char* ws = (char*)d_ws;
    size_t off = 0;
    auto alloc = [&](size_t bytes) {
        void* p = ws + off;
        off = (off + bytes + 255) & ~(size_t)255;
        return p;
    };
    bf16*  Xb    = (bf16*) alloc((size_t)MROWS * DMODEL * 2);
    bf16*  WinT  = (bf16*) alloc((size_t)4096  * DMODEL * 2);
    bf16*  xr    = (bf16*) alloc((size_t)MROWS * 4096  * 2);
    bf16*  ubf   = (bf16*) alloc((size_t)MROWS * DINNER * 2);
    bf16*  WxT   = (bf16*) alloc((size_t)128   * DINNER * 2);
    float* xdbl  = (float*)alloc((size_t)MROWS * 128 * 4);
    float* xdblp = (float*)alloc((size_t)8 * MROWS * 128 * 4);  // 8 split-K slices
    bf16*  drbf  = (bf16*) alloc((size_t)MROWS * 64 * 2);
    bf16*  WdtT  = (bf16*) alloc((size_t)DINNER * 64 * 2);
    bf16*  delta = (bf16*) alloc((size_t)MROWS * DINNER * 2);   // bf16
    bf16*  ybf   = (bf16*) alloc((size_t)MROWS * DINNER * 2);
    bf16*  WoutT = (bf16*) alloc((size_t)DMODEL * DINNER * 2);
    float* AS    = (float*)alloc((size_t)NCHUNK * 4096 * 32 * 4); // 32MB scan state

    // fused prep: 4 transposes + convert_x
    prep_kernel<<<6528 + (MROWS * DMODEL) / 256, 256, 0, stream>>>(
        W_in, WinT, W_x, WxT, W_dt, WdtT, W_out, WoutT, x, Xb);

    // GEMM1: x_and_res = Xb @ W_in -> xr bf16 (4096,4096) — 2-barrier deep pipe
    gemm256<<<dim3(4096 / 256, MROWS / 256), 512, 0, stream>>>(
        Xb, WinT, xr, 4096, 1024, 1024, 1024);
    // conv + silu -> u bf16 (vectorized, 8 ch/thread)
    conv_silu_kernel<<<(MROWS * DINNER / 8) / 256, 256, 0, stream>>>(
        xr, W_conv, b_conv, ubf);
    // GEMM2: x_dbl = u @ W_x, split-K x8 (256 blocks) -> partials
    gemm_bt<float, 0, true><<<dim3(1, MROWS / 128, 8), 512, 0, stream>>>(
        ubf, WxT, xdblp, nullptr, MROWS, 128, 256, 2048, 2048);
    reduce_xdbl<<<(MROWS * 128) / 256, 256, 0, stream>>>(xdblp, xdbl, drbf);
    // GEMM3: delta = softplus(delta_r @ W_dt + b_dt) -> bf16
    gemm_bt<bf16, 1><<<dim3(DINNER / 128, MROWS / 128), 512, 0, stream>>>(
        drbf, WdtT, delta, b_dt, MROWS, DINNER, 64, 64, 64);
    // chunked parallel selective scan -> ybf bf16
    scan_phase1<<<dim3(32, NCHUNK), 256, 0, stream>>>(delta, ubf, xdbl, A_log, AS);
    scan_phase2<<<256, 256, 0, stream>>>(AS);
    scan_phase3<<<dim3(32, NCHUNK), 256, 0, stream>>>(delta, ubf, xdbl, xr, AS,
                                                      A_log, Dp, ybf);
    // GEMM4: out = y @ W_out -> fp32 d_out, DIRECT (no split-K, no reduce)
    gemm_bt<float, 0><<<dim3(DMODEL / 128, MROWS / 128), 512, 0, stream>>>(
        ybf, WoutT, out, nullptr, MROWS, DMODEL, 2048, 2048, 2048);
}

// Round 19
// 238.031 us; speedup vs baseline: 1.0432x; 1.0432x over previous
//
#include <hip/hip_runtime.h>
#include <hip/hip_bf16.h>

#define L_SEQ  2048
#define NBATCH 2
#define DMODEL 1024
#define DINNER 2048
#define DSTATE 16
#define DTRANK 64
#define MROWS  (L_SEQ * NBATCH)   // 4096
#define NCHUNK 64
#define LCHUNK 32                 // L_SEQ / NCHUNK
#define LOG2E  1.44269504f

using bf16 = __hip_bfloat16;
typedef short s16x8 __attribute__((ext_vector_type(8)));   // 8 bf16 = 16B
typedef float f32x4 __attribute__((ext_vector_type(4)));

__device__ __forceinline__ void gload_lds16(const bf16* g, bf16* l) {
    __builtin_amdgcn_global_load_lds(
        (const __attribute__((address_space(1))) void*)g,
        (__attribute__((address_space(3))) void*)l, 16, 0, 0);
}

__device__ __forceinline__ float bf2f(short v) {
    return __uint_as_float(((unsigned)(unsigned short)v) << 16);
}

// ---------------------------------------------------------------------------
// 256x256 MFMA GEMM, 2-barrier deep pipeline (unchanged).
// ---------------------------------------------------------------------------
__global__ __launch_bounds__(512, 2)
void gemm256(const bf16* __restrict__ A, const bf16* __restrict__ Bt,
             bf16* __restrict__ C, int N, int K, int lda, int ldb)
{
    __shared__ __align__(16) bf16 As[2][256 * 64];
    __shared__ __align__(16) bf16 Bs[2][256 * 64];

    const int tid  = threadIdx.x;
    const int wid  = tid >> 6;
    const int lane = tid & 63;
    const int wr = wid >> 2, wc = wid & 3;       // 2x4 wave grid
    const int fr = lane & 15, fk = lane >> 4;

    const int orig = blockIdx.y * gridDim.x + blockIdx.x;
    const int xcd  = orig & 7, k = orig >> 3;
    const int byi  = (xcd >> 1) * 4 + (k >> 3);
    const int bxi  = (xcd & 1) * 8 + (k & 7);
    const long bm = (long)byi * 256;
    const long bn = (long)bxi * 256;

    const int q0 = tid, q1 = tid + 512;
    const int r0 = q0 >> 3, r1 = q1 >> 3;
    const int c0 = ((q0 & 7) ^ (r0 & 7)) << 3;
    const int c1 = ((q1 & 7) ^ (r1 & 7)) << 3;
    const bf16* sA0h0 = A  + (bm + r0)       * (long)lda + c0;
    const bf16* sA1h0 = A  + (bm + r1)       * (long)lda + c1;
    const bf16* sA0h1 = A  + (bm + 128 + r0) * (long)lda + c0;
    const bf16* sA1h1 = A  + (bm + 128 + r1) * (long)lda + c1;
    const bf16* sB0h0 = Bt + (bn + r0)       * (long)ldb + c0;
    const bf16* sB1h0 = Bt + (bn + r1)       * (long)ldb + c1;
    const bf16* sB0h1 = Bt + (bn + 128 + r0) * (long)ldb + c0;
    const bf16* sB1h1 = Bt + (bn + 128 + r1) * (long)ldb + c1;
    const int dst0 = wid * 512;
    const int dst1 = 4096 + wid * 512;

    const int o0   = ((fk ^ (fr & 7)) << 3);
    const int o1   = o0 ^ 32;
    const int rA64 = (wr * 64 + fr) * 64;
    const int rB64 = (wc * 32 + fr) * 64;

    f32x4 acc[8][4] = {};
    s16x8 af[4][2], bf0[2][2], bf1[2][2];
    const int nt = K >> 6;

#define STAGE(ARR, BUF, H, P0, P1) do {                    \
        gload_lds16(P0, &ARR[BUF][(H) * 8192 + dst0]);     \
        gload_lds16(P1, &ARR[BUF][(H) * 8192 + dst1]);     \
        P0 += 64; P1 += 64;                                \
    } while (0)

#define LOADA(MH, CUR) do {                                   \
        const bf16* ab = &As[CUR][rA64 + (MH) * 8192];        \
        _Pragma("unroll") for (int m = 0; m < 4; ++m) {       \
            af[m][0] = *(const s16x8*)&ab[m * 1024 + o0];     \
            af[m][1] = *(const s16x8*)&ab[m * 1024 + o1]; }   \
    } while (0)

#define LOADB(NH, CUR, BF) do {                               \
        const bf16* bb = &Bs[CUR][rB64 + (NH) * 8192];        \
        _Pragma("unroll") for (int n = 0; n < 2; ++n) {       \
            BF[n][0] = *(const s16x8*)&bb[n * 1024 + o0];     \
            BF[n][1] = *(const s16x8*)&bb[n * 1024 + o1]; }   \
    } while (0)

#define MFMAQ(MH, NH, BF) do {                                               \
        __builtin_amdgcn_s_setprio(1);                                       \
        _Pragma("unroll") for (int ks = 0; ks < 2; ++ks)                     \
        _Pragma("unroll") for (int m = 0; m < 4; ++m)                        \
        _Pragma("unroll") for (int n = 0; n < 2; ++n)                        \
            acc[(MH) * 4 + m][(NH) * 2 + n] =                                \
                __builtin_amdgcn_mfma_f32_16x16x32_bf16(                     \
                    af[m][ks], BF[n][ks], acc[(MH) * 4 + m][(NH) * 2 + n],   \
                    0, 0, 0);                                                \
        __builtin_amdgcn_s_setprio(0);                                       \
    } while (0)

#define WB(NV) asm volatile("s_waitcnt vmcnt(" #NV ")\n\ts_barrier" ::: "memory")

    STAGE(As, 0, 0, sA0h0, sA1h0);
    STAGE(Bs, 0, 0, sB0h0, sB1h0);
    STAGE(Bs, 0, 1, sB0h1, sB1h1);
    STAGE(As, 0, 1, sA0h1, sA1h1);

    int cur = 0;
    for (int t = 0; t < nt; ++t) {
        WB(2);                               // A0,B0,B1 of t ready; A1 in flight
        LOADA(0, cur);
        LOADB(0, cur, bf0);
        LOADB(1, cur, bf1);
        if (t + 1 < nt) {
            STAGE(As, cur ^ 1, 0, sA0h0, sA1h0);
            STAGE(Bs, cur ^ 1, 0, sB0h0, sB1h0);
            STAGE(Bs, cur ^ 1, 1, sB0h1, sB1h1);
            STAGE(As, cur ^ 1, 1, sA0h1, sA1h1);
        }
        MFMAQ(0, 0, bf0);
        MFMAQ(0, 1, bf1);
        if (t + 1 < nt) WB(8); else WB(0);   // A1 of t ready
        LOADA(1, cur);
        MFMAQ(1, 1, bf1);
        MFMAQ(1, 0, bf0);
        cur ^= 1;
    }

#undef STAGE
#undef LOADA
#undef LOADB
#undef MFMAQ
#undef WB

    #pragma unroll
    for (int mh = 0; mh < 2; ++mh)
    #pragma unroll
    for (int m = 0; m < 4; ++m)
    #pragma unroll
    for (int nh = 0; nh < 2; ++nh)
    #pragma unroll
    for (int n = 0; n < 2; ++n) {
        f32x4 v = acc[mh * 4 + m][nh * 2 + n];
        long row0 = bm + wr * 64 + mh * 128 + m * 16 + fk * 4;
        long col  = bn + wc * 32 + nh * 128 + n * 16 + fr;
        #pragma unroll
        for (int j = 0; j < 4; ++j)
            C[(row0 + j) * N + col] = __float2bfloat16(v[j]);
    }
}

// ---------------------------------------------------------------------------
// MFMA bf16 GEMM: 128x128 tile, BK=32, 512 threads = 8 waves, counted 2-deep
// pipeline (unchanged).
// ---------------------------------------------------------------------------
template<typename OutT, int EPI, bool SPLITK = false>
__global__ __launch_bounds__(512)
void gemm_bt(const bf16* __restrict__ A, const bf16* __restrict__ Bt,
             OutT* __restrict__ C, const float* __restrict__ bias,
             int M, int N, int K, int lda, int ldb)
{
    __shared__ __align__(16) bf16 As[2][128 * 32];
    __shared__ __align__(16) bf16 Bs[2][128 * 32];

    const int tid  = threadIdx.x;
    const int wid  = tid >> 6;
    const int lane = tid & 63;
    const int wr = wid >> 1, wc = wid & 1;
    const int fr = lane & 15, fk = lane >> 4;

    const int nbx = gridDim.x;
    const int nwg = nbx * gridDim.y;
    int id  = blockIdx.y * nbx + blockIdx.x;
    if (nwg >= 8) {
        int cpx = nwg >> 3;
        id = (id & 7) * cpx + (id >> 3);
    }
    const int bxi = id % nbx, byi = id / nbx;
    const long bm = (long)byi * 128;
    const long bn = (long)bxi * 128;

    if constexpr (SPLITK) {
        long ko = (long)blockIdx.z * K;
        A  += ko;
        Bt += ko;
        C  += (size_t)blockIdx.z * M * N;
    }

    const int r0 = tid >> 2, c0 = (tid & 3) << 3;
    const bf16* pA = A  + (bm + r0) * (long)lda + c0;
    const bf16* pB = Bt + (bn + r0) * (long)ldb + c0;
    const size_t ld = (size_t)wid * 512;

    f32x4 acc[2][4] = {};
    const int nt = K >> 5;

#define STG(BUF) do {                             \
        gload_lds16(pA, &As[BUF][ld]);            \
        gload_lds16(pB, &Bs[BUF][ld]);            \
        pA += 32; pB += 32;                       \
    } while (0)

    STG(0);
    if (nt > 1) STG(1);

    int cur = 0;
    for (int t = 0; t < nt; ++t) {
        if (t + 1 < nt)
            asm volatile("s_waitcnt vmcnt(2)\n\ts_barrier" ::: "memory");
        else
            asm volatile("s_waitcnt vmcnt(0)\n\ts_barrier" ::: "memory");

        s16x8 afrag[2], bfrag[4];
        #pragma unroll
        for (int m = 0; m < 2; ++m)
            afrag[m] = *(const s16x8*)&As[cur][(wr * 32 + m * 16 + fr) * 32 + fk * 8];
        #pragma unroll
        for (int n = 0; n < 4; ++n)
            bfrag[n] = *(const s16x8*)&Bs[cur][(wc * 64 + n * 16 + fr) * 32 + fk * 8];

        #pragma unroll
        for (int m = 0; m < 2; ++m)
            #pragma unroll
            for (int n = 0; n < 4; ++n)
                acc[m][n] = __builtin_amdgcn_mfma_f32_16x16x32_bf16(
                    afrag[m], bfrag[n], acc[m][n], 0, 0, 0);

        if (t + 2 < nt) {
            asm volatile("s_waitcnt lgkmcnt(0)\n\ts_barrier" ::: "memory");
            STG(cur);
        }
        cur ^= 1;
    }
#undef STG

    #pragma unroll
    for (int m = 0; m < 2; ++m)
        #pragma unroll
        for (int n = 0; n < 4; ++n) {
            f32x4 v = acc[m][n];
            long row0 = bm + wr * 32 + m * 16 + fk * 4;
            long col  = bn + wc * 64 + n * 16 + fr;
            #pragma unroll
            for (int j = 0; j < 4; ++j) {
                float val = v[j];
                if (EPI == 1) {
                    val += bias[col];
                    val = (val > 20.f) ? val : log1pf(__expf(val));
                }
                if constexpr (sizeof(OutT) == 2)
                    C[(row0 + j) * N + col] = __float2bfloat16(val);
                else
                    C[(row0 + j) * N + col] = val;
            }
        }
}

// ---------------------------------------------------------------------------
// Fused preprocessing: 4 weight transposes + convert_x (unchanged)
// ---------------------------------------------------------------------------
__device__ __forceinline__ void do_transpose(
    const float* __restrict__ in, bf16* __restrict__ out,
    int R, int C, int Cpad, int bx, int by, int tx, int ty)
{
    __shared__ float tile[32][33];
    int cb = bx * 32, rb = by * 32;
    #pragma unroll
    for (int i = 0; i < 4; ++i) {
        int r = rb + ty + i * 8, c = cb + tx;
        tile[ty + i * 8][tx] = (r < R && c < C) ? in[(long)r * C + c] : 0.f;
    }
    __syncthreads();
    #pragma unroll
    for (int i = 0; i < 4; ++i) {
        int oc = cb + ty + i * 8;
        int orow = rb + tx;
        if (oc < Cpad && orow < R)
            out[(long)oc * R + orow] = __float2bfloat16(tile[tx][ty + i * 8]);
    }
}

__global__ __launch_bounds__(256)
void prep_kernel(const float* __restrict__ W_in,  bf16* __restrict__ WinT,
                 const float* __restrict__ W_x,   bf16* __restrict__ WxT,
                 const float* __restrict__ W_dt,  bf16* __restrict__ WdtT,
                 const float* __restrict__ W_out, bf16* __restrict__ WoutT,
                 const float* __restrict__ x,     bf16* __restrict__ Xb)
{
    const int b  = blockIdx.x;
    const int t  = threadIdx.x;
    const int tx = t & 31, ty = t >> 5;

    if (b < 4096) {
        do_transpose(W_in, WinT, 1024, 4096, 4096, b & 127, b >> 7, tx, ty);
    } else if (b < 4352) {
        int b2 = b - 4096;
        do_transpose(W_x, WxT, 2048, 96, 128, b2 & 3, b2 >> 2, tx, ty);
    } else if (b < 4480) {
        int b3 = b - 4352;
        do_transpose(W_dt, WdtT, 64, 2048, 2048, b3 & 63, b3 >> 6, tx, ty);
    } else if (b < 6528) {
        int b4 = b - 4480;
        do_transpose(W_out, WoutT, 2048, 1024, 1024, b4 & 31, b4 >> 5, tx, ty);
    } else {
        int idx = (b - 6528) * 256 + t;
        int c   = idx & (DMODEL - 1);
        int row = idx >> 10;
        int l   = row & (L_SEQ - 1);
        int bb  = row >> 11;
        Xb[idx] = __float2bfloat16(x[((l * NBATCH + bb) << 10) | c]);
    }
}

// depthwise causal conv (d_conv=4) + silu, 8 channels per thread (unchanged)
__global__ void conv_silu_kernel(const bf16* __restrict__ xr, const float* __restrict__ Wc,
                                 const float* __restrict__ bc, bf16* __restrict__ u)
{
    int idx = blockIdx.x * 256 + threadIdx.x;
    int g   = idx & 255;
    int row = idx >> 8;
    int c   = g << 3;
    int l   = row & (L_SEQ - 1);

    float acc[8];
    f32x4 bi0 = *(const f32x4*)(bc + c);
    f32x4 bi1 = *(const f32x4*)(bc + c + 4);
    #pragma unroll
    for (int j = 0; j < 4; ++j) { acc[j] = bi0[j]; acc[4 + j] = bi1[j]; }

    f32x4 w[8];
    #pragma unroll
    for (int j = 0; j < 8; ++j) w[j] = *(const f32x4*)(Wc + (c + j) * 4);

    #pragma unroll
    for (int t = 0; t < 4; ++t) {
        int ll = l - 3 + t;
        if (ll >= 0) {
            s16x8 v = *(const s16x8*)(xr + (long)(row - 3 + t) * 4096 + c);
            #pragma unroll
            for (int j = 0; j < 8; ++j)
                acc[j] += bf2f(v[j]) * w[j][t];
        }
    }
    s16x8 o;
    #pragma unroll
    for (int j = 0; j < 8; ++j) {
        float a = acc[j];
        float s = a / (1.f + __builtin_amdgcn_exp2f(-LOG2E * a));
        bf16 h = __float2bfloat16(s);
        o[j] = *(short*)&h;
    }
    *(s16x8*)(u + (long)row * DINNER + c) = o;
}

// sum 8 split-K partials -> xdbl fp32; also emit drbf (cols 0..63 as bf16)
__global__ void reduce_xdbl(const float* __restrict__ part, float* __restrict__ xdbl,
                            bf16* __restrict__ drbf)
{
    int idx = blockIdx.x * 256 + threadIdx.x;
    const size_t stride = (size_t)MROWS * 128;
    float v = 0.f;
    #pragma unroll
    for (int z = 0; z < 8; ++z)
        v += part[idx + z * stride];
    xdbl[idx] = v;
    int col = idx & 127;
    if (col < 64)
        drbf[(idx >> 7) * 64 + col] = __float2bfloat16(v);
}

// ---------------------------------------------------------------------------
// Chunked parallel selective scan — round-9 inner loops (frozen), with the
// block-uniform xdbl B/C panel preloaded into LDS (4KB): B/C reads become
// same-address ds_read broadcasts, removing 2 (p1) / 4 (p3) VMEM ops per
// step from the L2/L3 path. b and chunk are block-uniform so the panel is
// shared by all 256 threads.
// ---------------------------------------------------------------------------
__global__ __launch_bounds__(256)
void scan_phase1(const bf16* __restrict__ delta, const bf16* __restrict__ u,
                 const float* __restrict__ xdbl, const float* __restrict__ A_log,
                 float* __restrict__ AS)
{
    __shared__ __align__(16) float smB[LCHUNK][16];   // B panel: 2KB

    const int idx   = blockIdx.x * 256 + threadIdx.x;
    const int half  = idx & 1;
    const int ch    = idx >> 1;
    const int chunk = blockIdx.y;
    const int d     = ch & (DINNER - 1);
    const int b     = ch >> 11;                       // block-uniform
    const int n0    = half * 8;

    const long row0 = (long)b * L_SEQ + chunk * LCHUNK;

    // preload B panel: 512 floats, threads 0..127 load f32x4 each
    {
        const int t = threadIdx.x;
        if (t < 128) {
            int r = t >> 2, c = (t & 3) << 2;
            *(f32x4*)&smB[r][c] = *(const f32x4*)(xdbl + (row0 + r) * 128 + 64 + c);
        }
    }

    float A2[8], s[8];
    const f32x4* Arow = (const f32x4*)(A_log + d * DSTATE + n0);
    #pragma unroll
    for (int q = 0; q < 2; ++q) {
        f32x4 v = Arow[q];
        #pragma unroll
        for (int j = 0; j < 4; ++j) A2[q * 4 + j] = -__expf(v[j]) * LOG2E;
    }
    #pragma unroll
    for (int n = 0; n < 8; ++n) s[n] = 0.f;
    float sdl = 0.f;

    bool fastA = true;
    #pragma unroll
    for (int j = 0; j < 8; ++j)
        fastA &= fabsf(A2[j] + (float)(n0 + j + 1) * LOG2E)
                 < 0.01f * (float)(n0 + j + 1);

    const bf16*  pD = delta + row0 * DINNER + d;
    const bf16*  pU = u     + row0 * DINNER + d;

    __syncthreads();

    if (fastA) {
        #pragma unroll 4
        for (int l = 0; l < LCHUNK; ++l) {
            float dl = __bfloat162float(*pD);
            float uv = __bfloat162float(*pU);
            f32x4 B0 = *(const f32x4*)&smB[l][n0];
            f32x4 B1 = *(const f32x4*)&smB[l][n0 + 4];
            pD += DINNER; pU += DINNER;
            float dbu = dl * uv;
            sdl += dl;
            float b1 = __builtin_amdgcn_exp2f(-LOG2E * dl);   // exp(-dl)
            float b2 = b1 * b1, b3 = b2 * b1, b4 = b2 * b2;
            float b5 = b4 * b1, b6 = b4 * b2, b7 = b4 * b3, b8 = b4 * b4;
            float pre = half ? b8 : 1.f;
            s[0] = pre * b1 * s[0] + dbu * B0[0];
            s[1] = pre * b2 * s[1] + dbu * B0[1];
            s[2] = pre * b3 * s[2] + dbu * B0[2];
            s[3] = pre * b4 * s[3] + dbu * B0[3];
            s[4] = pre * b5 * s[4] + dbu * B1[0];
            s[5] = pre * b6 * s[5] + dbu * B1[1];
            s[6] = pre * b7 * s[6] + dbu * B1[2];
            s[7] = pre * b8 * s[7] + dbu * B1[3];
        }
    } else {
        #pragma unroll 4
        for (int l = 0; l < LCHUNK; ++l) {
            float dl = __bfloat162float(*pD);
            float uv = __bfloat162float(*pU);
            f32x4 B0 = *(const f32x4*)&smB[l][n0];
            f32x4 B1 = *(const f32x4*)&smB[l][n0 + 4];
            pD += DINNER; pU += DINNER;
            float dbu = dl * uv;
            sdl += dl;
            #pragma unroll
            for (int j = 0; j < 4; ++j) {
                float e = __builtin_amdgcn_exp2f(dl * A2[j]);
                s[j] = e * s[j] + dbu * B0[j];
            }
            #pragma unroll
            for (int j = 0; j < 4; ++j) {
                float e = __builtin_amdgcn_exp2f(dl * A2[4 + j]);
                s[4 + j] = e * s[4 + j] + dbu * B1[j];
            }
        }
    }
    float ap[8];
    #pragma unroll
    for (int n = 0; n < 8; ++n) ap[n] = __builtin_amdgcn_exp2f(sdl * A2[n]);

    float* o = AS + ((size_t)chunk * 4096 + ch) * 32 + n0;
    *(f32x4*)(o)      = *(f32x4*)&ap[0];
    *(f32x4*)(o + 4)  = *(f32x4*)&ap[4];
    *(f32x4*)(o + 16) = *(f32x4*)&s[0];
    *(f32x4*)(o + 20) = *(f32x4*)&s[4];
}

__global__ __launch_bounds__(256)
void scan_phase2(float* __restrict__ AS)
{
    const int idx = blockIdx.x * 256 + threadIdx.x;
    const int n   = idx & 15;
    const int ch  = idx >> 4;

    float s = 0.f;
    for (int cb = 0; cb < NCHUNK; cb += 16) {
        float av[16], sv[16];
        #pragma unroll
        for (int j = 0; j < 16; ++j) {
            size_t r = ((size_t)(cb + j) * 4096 + ch) * 32 + n;
            av[j] = AS[r];
            sv[j] = AS[r + 16];
        }
        #pragma unroll
        for (int j = 0; j < 16; ++j) {
            AS[((size_t)(cb + j) * 4096 + ch) * 32 + 16 + n] = s;
            s = av[j] * s + sv[j];
        }
    }
}

__global__ __launch_bounds__(256)
void scan_phase3(const bf16* __restrict__ delta, const bf16* __restrict__ u,
                 const float* __restrict__ xdbl, const bf16* __restrict__ xr,
                 const float* __restrict__ AS, const float* __restrict__ A_log,
                 const float* __restrict__ Dp, bf16* __restrict__ ybf)
{
    __shared__ __align__(16) float smBC[LCHUNK][32];  // B|C panel: 4KB

    const int idx   = blockIdx.x * 256 + threadIdx.x;
    const int half  = idx & 1;
    const int ch    = idx >> 1;
    const int chunk = blockIdx.y;
    const int d     = ch & (DINNER - 1);
    const int b     = ch >> 11;                       // block-uniform
    const int n0    = half * 8;

    const long row0 = (long)b * L_SEQ + chunk * LCHUNK;

    // preload B|C panel: 1024 floats, 256 threads load f32x4 each
    {
        const int t = threadIdx.x;
        int r = t >> 3, c = (t & 7) << 2;
        *(f32x4*)&smBC[r][c] = *(const f32x4*)(xdbl + (row0 + r) * 128 + 64 + c);
    }

    float A2[8], s[8];
    const f32x4* Arow = (const f32x4*)(A_log + d * DSTATE + n0);
    #pragma unroll
    for (int q = 0; q < 2; ++q) {
        f32x4 v = Arow[q];
        #pragma unroll
        for (int j = 0; j < 4; ++j) A2[q * 4 + j] = -__expf(v[j]) * LOG2E;
    }
    const float* ip = AS + ((size_t)chunk * 4096 + ch) * 32 + 16 + n0;
    *(f32x4*)&s[0] = *(const f32x4*)(ip);
    *(f32x4*)&s[4] = *(const f32x4*)(ip + 4);

    bool fastA = true;
    #pragma unroll
    for (int j = 0; j < 8; ++j)
        fastA &= fabsf(A2[j] + (float)(n0 + j + 1) * LOG2E)
                 < 0.01f * (float)(n0 + j + 1);

    const float Dd  = Dp[d];
    const bf16*  pD = delta + row0 * DINNER + d;
    const bf16*  pU = u     + row0 * DINNER + d;
    const bf16*  pR = xr    + row0 * 4096 + 2048 + d;
    bf16*        pY = ybf   + row0 * DINNER + d;

    __syncthreads();

    if (fastA) {
        #pragma unroll 4
        for (int l = 0; l < LCHUNK; ++l) {
            float dl = __bfloat162float(*pD);
            float uv = __bfloat162float(*pU);
            float rs = __bfloat162float(*pR);
            f32x4 B0 = *(const f32x4*)&smBC[l][n0];
            f32x4 B1 = *(const f32x4*)&smBC[l][n0 + 4];
            f32x4 C0 = *(const f32x4*)&smBC[l][16 + n0];
            f32x4 C1 = *(const f32x4*)&smBC[l][16 + n0 + 4];
            pD += DINNER; pU += DINNER; pR += 4096;
            float dbu = dl * uv;
            float b1 = __builtin_amdgcn_exp2f(-LOG2E * dl);   // exp(-dl)
            float b2 = b1 * b1, b3 = b2 * b1, b4 = b2 * b2;
            float b5 = b4 * b1, b6 = b4 * b2, b7 = b4 * b3, b8 = b4 * b4;
            float pre = half ? b8 : 1.f;
            float y0 = 0.f, y1 = 0.f;
            s[0] = pre * b1 * s[0] + dbu * B0[0];  y0 += s[0] * C0[0];
            s[1] = pre * b2 * s[1] + dbu * B0[1];  y0 += s[1] * C0[1];
            s[2] = pre * b3 * s[2] + dbu * B0[2];  y0 += s[2] * C0[2];
            s[3] = pre * b4 * s[3] + dbu * B0[3];  y0 += s[3] * C0[3];
            s[4] = pre * b5 * s[4] + dbu * B1[0];  y1 += s[4] * C1[0];
            s[5] = pre * b6 * s[5] + dbu * B1[1];  y1 += s[5] * C1[1];
            s[6] = pre * b7 * s[6] + dbu * B1[2];  y1 += s[6] * C1[2];
            s[7] = pre * b8 * s[7] + dbu * B1[3];  y1 += s[7] * C1[3];
            float yh = y0 + y1;
            float yt = yh + __shfl_xor(yh, 1);
            if (half == 0) {
                float yf = yt + uv * Dd;
                yf *= rs / (1.f + __builtin_amdgcn_exp2f(-LOG2E * rs));
                *pY = __float2bfloat16(yf);
            }
            pY += DINNER;
        }
    } else {
        #pragma unroll 4
        for (int l = 0; l < LCHUNK; ++l) {
            float dl = __bfloat162float(*pD);
            float uv = __bfloat162float(*pU);
            float rs = __bfloat162float(*pR);
            f32x4 B0 = *(const f32x4*)&smBC[l][n0];
            f32x4 B1 = *(const f32x4*)&smBC[l][n0 + 4];
            f32x4 C0 = *(const f32x4*)&smBC[l][16 + n0];
            f32x4 C1 = *(const f32x4*)&smBC[l][16 + n0 + 4];
            pD += DINNER; pU += DINNER; pR += 4096;
            float dbu = dl * uv;
            float y0 = 0.f, y1 = 0.f;
            #pragma unroll
            for (int j = 0; j < 4; ++j) {
                float e = __builtin_amdgcn_exp2f(dl * A2[j]);
                s[j] = e * s[j] + dbu * B0[j];
                y0 += s[j] * C0[j];
            }
            #pragma unroll
            for (int j = 0; j < 4; ++j) {
                float e = __builtin_amdgcn_exp2f(dl * A2[4 + j]);
                s[4 + j] = e * s[4 + j] + dbu * B1[j];
                y1 += s[4 + j] * C1[j];
            }
            float yh = y0 + y1;
            float yt = yh + __shfl_xor(yh, 1);
            if (half == 0) {
                float yf = yt + uv * Dd;
                yf *= rs / (1.f + __builtin_amdgcn_exp2f(-LOG2E * rs));
                *pY = __float2bfloat16(yf);
            }
            pY += DINNER;
        }
    }
}

// ---------------------------------------------------------------------------
extern "C" void kernel_launch(void* const* d_in, const int* in_sizes, int n_in,
                              void* d_out, int out_size, void* d_ws, size_t ws_size,
                              hipStream_t stream)
{
    const float* x      = (const float*)d_in[0];
    const float* W_in   = (const float*)d_in[1];
    const float* W_conv = (const float*)d_in[2];
    const float* b_conv = (const float*)d_in[3];
    const float* W_x    = (const float*)d_in[4];
    const float* W_dt   = (const float*)d_in[5];
    const float* b_dt   = (const float*)d_in[6];
    const float* A_log  = (const float*)d_in[7];
    const float* Dp     = (const float*)d_in[8];
    const float* W_out  = (const float*)d_in[9];
    float* out = (float*)d_out;

    char* ws = (char*)d_ws;
    size_t off = 0;
    auto alloc = [&](size_t bytes) {
        void* p = ws + off;
        off = (off + bytes + 255) & ~(size_t)255;
        return p;
    };
    bf16*  Xb    = (bf16*) alloc((size_t)MROWS * DMODEL * 2);
    bf16*  WinT  = (bf16*) alloc((size_t)4096  * DMODEL * 2);
    bf16*  xr    = (bf16*) alloc((size_t)MROWS * 4096  * 2);
    bf16*  ubf   = (bf16*) alloc((size_t)MROWS * DINNER * 2);
    bf16*  WxT   = (bf16*) alloc((size_t)128   * DINNER * 2);
    float* xdbl  = (float*)alloc((size_t)MROWS * 128 * 4);
    float* xdblp = (float*)alloc((size_t)8 * MROWS * 128 * 4);  // 8 split-K slices
    bf16*  drbf  = (bf16*) alloc((size_t)MROWS * 64 * 2);
    bf16*  WdtT  = (bf16*) alloc((size_t)DINNER * 64 * 2);
    bf16*  delta = (bf16*) alloc((size_t)MROWS * DINNER * 2);   // bf16
    bf16*  ybf   = (bf16*) alloc((size_t)MROWS * DINNER * 2);
    bf16*  WoutT = (bf16*) alloc((size_t)DMODEL * DINNER * 2);
    float* AS    = (float*)alloc((size_t)NCHUNK * 4096 * 32 * 4); // 32MB scan state

    // fused prep: 4 transposes + convert_x
    prep_kernel<<<6528 + (MROWS * DMODEL) / 256, 256, 0, stream>>>(
        W_in, WinT, W_x, WxT, W_dt, WdtT, W_out, WoutT, x, Xb);

    // GEMM1: x_and_res = Xb @ W_in -> xr bf16 (4096,4096) — 2-barrier deep pipe
    gemm256<<<dim3(4096 / 256, MROWS / 256), 512, 0, stream>>>(
        Xb, WinT, xr, 4096, 1024, 1024, 1024);
    // conv + silu -> u bf16 (vectorized, 8 ch/thread)
    conv_silu_kernel<<<(MROWS * DINNER / 8) / 256, 256, 0, stream>>>(
        xr, W_conv, b_conv, ubf);
    // GEMM2: x_dbl = u @ W_x, split-K x8 (256 blocks) -> partials
    gemm_bt<float, 0, true><<<dim3(1, MROWS / 128, 8), 512, 0, stream>>>(
        ubf, WxT, xdblp, nullptr, MROWS, 128, 256, 2048, 2048);
    reduce_xdbl<<<(MROWS * 128) / 256, 256, 0, stream>>>(xdblp, xdbl, drbf);
    // GEMM3: delta = softplus(delta_r @ W_dt + b_dt) -> bf16
    gemm_bt<bf16, 1><<<dim3(DINNER / 128, MROWS / 128), 512, 0, stream>>>(
        drbf, WdtT, delta, b_dt, MROWS, DINNER, 64, 64, 64);
    // chunked parallel selective scan -> ybf bf16
    scan_phase1<<<dim3(32, NCHUNK), 256, 0, stream>>>(delta, ubf, xdbl, A_log, AS);
    scan_phase2<<<256, 256, 0, stream>>>(AS);
    scan_phase3<<<dim3(32, NCHUNK), 256, 0, stream>>>(delta, ubf, xdbl, xr, AS,
                                                      A_log, Dp, ybf);
    // GEMM4: out = y @ W_out -> fp32 d_out, DIRECT (no split-K, no reduce)
    gemm_bt<float, 0><<<dim3(DMODEL / 128, MROWS / 128), 512, 0, stream>>>(
        ybf, WoutT, out, nullptr, MROWS, DMODEL, 2048, 2048, 2048);
}